// Round 1
// 654.347 us; speedup vs baseline: 1.0816x; 1.0816x over previous
//
#include <hip/hip_runtime.h>
#include <cstdint>
#include <cstddef>

// ---- problem constants ----
#define Hd    3584
#define NHq   28
#define NKVh  4
#define Dh    128
#define GRP   7
#define Bb    4
#define Ss    1024
#define Tt    4096
#define NBLK  512
#define BSZ   16
#define QKVO  4608
#define ATTN_SCALE 0.08838834764831845f  // 1/sqrt(128)

typedef short s8v __attribute__((ext_vector_type(8)));   // 8 x bf16 (4 VGPRs)
typedef float f4v __attribute__((ext_vector_type(4)));   // 4 x f32 accum

__device__ __forceinline__ ushort bf16r(float f) {       // RNE f32->bf16
    uint32_t u = __float_as_uint(f);
    u += 0x7fff + ((u >> 16) & 1);
    return (ushort)(u >> 16);
}

__device__ __forceinline__ uint32_t pkbf(float a, float b) {  // pack 2 bf16 -> b32
    return (uint32_t)bf16r(a) | ((uint32_t)bf16r(b) << 16);
}

__device__ __forceinline__ f4v mfma16(s8v a, s8v b, f4v c) {
    return __builtin_amdgcn_mfma_f32_16x16x32_bf16(a, b, c, 0, 0, 0);
}

// async global->LDS, 16B per lane; LDS dest = wave-uniform base + lane*16
__device__ __forceinline__ void async_cp16(ushort* lds, const ushort* g) {
    __builtin_amdgcn_global_load_lds(
        (const __attribute__((address_space(1))) uint32_t*)(uintptr_t)g,
        (__attribute__((address_space(3))) uint32_t*)(uintptr_t)lds,
        16, 0, 0);
}

// ---------------- fp32 -> bf16 convert (vectorized) ----------------
__global__ __launch_bounds__(256) void cvt_bf16(const float* __restrict__ src,
                                                ushort* __restrict__ dst, int n4) {
    int i = blockIdx.x * 256 + threadIdx.x;
    if (i >= n4) return;
    float4 f = ((const float4*)src)[i];
    ushort4 u;
    u.x = bf16r(f.x); u.y = bf16r(f.y); u.z = bf16r(f.z); u.w = bf16r(f.w);
    ((ushort4*)dst)[i] = u;
}

// ---------------- cache passthrough copy ----------------
__global__ __launch_bounds__(256) void copy_f4(const float* __restrict__ src,
                                               float* __restrict__ dst, int n4) {
    int i = blockIdx.x * 256 + threadIdx.x;
    if (i < n4) ((float4*)dst)[i] = ((const float4*)src)[i];
}

// ---------------- O-proj GEMM: C[M,N] = A[M,K] @ Bw[N,K]^T ----------------
// 256x256 tile, BK=32, TRIPLE-buffered K-pipeline (96 KB LDS, 1 blk/CU):
// stage tile t+2 while computing tile t; raw s_barrier (no implicit drain);
// counted s_waitcnt vmcnt(4) ONCE per K-tile (per-wave: exactly 4 stage
// issues/tile, so vmcnt(4) at end of tile t proves everything older than
// tile t's own issues landed -> buf[(t)%3]-for-tile-t staged at t-2 is safe,
// with ~1.5 tiles of HBM-latency slack). 8 waves 4Mx2N, per-wave 64x128 out.
// Fragment chunk swizzle chunk ^= (row>>1)&3 (2-way = free) kept from r3.
__global__ __launch_bounds__(512, 2) void gemm_bt(
    const ushort* __restrict__ A, const ushort* __restrict__ Bw,
    float* __restrict__ C, int N, int K)
{
    __shared__ ushort As[3][256 * 32];
    __shared__ ushort Bs[3][256 * 32];
    const int tid  = threadIdx.x;
    const int wv   = tid >> 6;
    const int lane = tid & 63;
    const int quad = lane >> 4;
    const int l16  = lane & 15;
    const int m0 = blockIdx.y * 256;
    const int n0 = blockIdx.x * 256;
    const int wm = (wv >> 1) * 64;
    const int wn = (wv & 1) * 128;

    f4v zero = {0.f, 0.f, 0.f, 0.f};
    f4v acc[4][8];
    #pragma unroll
    for (int i = 0; i < 4; i++)
        #pragma unroll
        for (int j = 0; j < 8; j++) acc[i][j] = zero;

    // staging: per wave 32 rows of A and 32 rows of B per tile (2 calls each).
    // swizzled source chunk is lane-pure: (l&3) ^ ((l>>3)&3)  (== (row>>1)&3)
    const int swz = ((lane & 3) ^ ((lane >> 3) & 3)) * 8;
    const int rS  = lane >> 2;                       // row within 16-row slab
    const ushort* gA = A  + (size_t)(m0 + wv * 32 + rS) * K + swz;
    const ushort* gB = Bw + (size_t)(n0 + wv * 32 + rS) * K + swz;
    const int stA = (wv * 32) * 32;                  // LDS slab base (ushorts)
    const int fsw = ((l16 >> 1) & 3) * 8;            // fragment chunk xor

    // prologue: stage tiles 0 and 1 (8 issues/wave), wait for tile 0 (4 oldest)
    #pragma unroll
    for (int t = 0; t < 2; t++) {
        async_cp16(&As[t][stA],           gA + t * 32);
        async_cp16(&As[t][stA + 16 * 32], gA + (size_t)16 * K + t * 32);
        async_cp16(&Bs[t][stA],           gB + t * 32);
        async_cp16(&Bs[t][stA + 16 * 32], gB + (size_t)16 * K + t * 32);
    }
    asm volatile("s_waitcnt vmcnt(4)" ::: "memory");
    __builtin_amdgcn_s_barrier();

    const int NT = K / 32;
    for (int t = 0; t < NT; t++) {
        const ushort* Ac = As[t % 3];
        const ushort* Bc = Bs[t % 3];
        ushort* An = (ushort*)As[(t + 2) % 3];
        ushort* Bn = (ushort*)Bs[(t + 2) % 3];
        const int kn = (t + 2) * 32;
        const bool pf = (t + 2 < NT);

        // ---- phase 0: n-frags 0..3 ----
        s8v af[4], bfr[4];
        #pragma unroll
        for (int i = 0; i < 4; i++)
            af[i] = *(const s8v*)&Ac[(wm + i * 16 + l16) * 32 + ((quad * 8) ^ fsw)];
        #pragma unroll
        for (int j = 0; j < 4; j++)
            bfr[j] = *(const s8v*)&Bc[(wn + j * 16 + l16) * 32 + ((quad * 8) ^ fsw)];
        if (pf) {
            async_cp16(&An[stA], gA + kn);
            async_cp16(&Bn[stA], gB + kn);
        }
        __builtin_amdgcn_s_barrier();
        asm volatile("s_waitcnt lgkmcnt(0)" ::: "memory");
        __builtin_amdgcn_sched_barrier(0);
        __builtin_amdgcn_s_setprio(1);
        #pragma unroll
        for (int i = 0; i < 4; i++)
            #pragma unroll
            for (int j = 0; j < 4; j++)
                acc[i][j] = mfma16(af[i], bfr[j], acc[i][j]);
        __builtin_amdgcn_s_setprio(0);
        __builtin_amdgcn_s_barrier();

        // ---- phase 1: n-frags 4..7 (af reused in regs) ----
        #pragma unroll
        for (int j = 0; j < 4; j++)
            bfr[j] = *(const s8v*)&Bc[(wn + (j + 4) * 16 + l16) * 32 + ((quad * 8) ^ fsw)];
        if (pf) {
            async_cp16(&An[stA + 16 * 32], gA + (size_t)16 * K + kn);
            async_cp16(&Bn[stA + 16 * 32], gB + (size_t)16 * K + kn);
            asm volatile("s_waitcnt vmcnt(4)" ::: "memory");   // keep only this tile's 4
        } else {
            asm volatile("s_waitcnt vmcnt(0)" ::: "memory");   // tail drain
        }
        __builtin_amdgcn_s_barrier();
        asm volatile("s_waitcnt lgkmcnt(0)" ::: "memory");
        __builtin_amdgcn_sched_barrier(0);
        __builtin_amdgcn_s_setprio(1);
        #pragma unroll
        for (int i = 0; i < 4; i++)
            #pragma unroll
            for (int j = 0; j < 4; j++)
                acc[i][j + 4] = mfma16(af[i], bfr[j], acc[i][j + 4]);
        __builtin_amdgcn_s_setprio(0);
        __builtin_amdgcn_s_barrier();
    }

    #pragma unroll
    for (int i = 0; i < 4; i++) {
        const int m = m0 + wm + i * 16 + quad * 4;
        #pragma unroll
        for (int j = 0; j < 8; j++) {
            const int n = n0 + wn + j * 16 + l16;
            float* cp = C + (size_t)m * N + n;
            #pragma unroll
            for (int r = 0; r < 4; r++)
                cp[(size_t)r * N] = acc[i][j][r];
        }
    }
}

// ---------------- fused QKV GEMM + bias + RoPE + scatter ----------------
// 128x256 tile (2 head slots/block), BK=32, triple-buffered pipeline,
// 72 KB LDS -> 2 blk/CU (launch_bounds(512,4) caps VGPR at 128).
// 8 waves 4Mx2N: wave owns 32 tokens x 1 full head slot (128 cols), so the
// RoPE partner d^64 stays in fragment j^4 of the SAME lane. Per wave per
// tile: 3 stage issues (A x1, B x2) -> counted vmcnt(3) once per tile.
__global__ __launch_bounds__(512, 4) void gemm_qkv(
    const ushort* __restrict__ A, const ushort* __restrict__ Bw,
    const float* __restrict__ bias, const int* __restrict__ pos,
    const int* __restrict__ slot_map,
    ushort* __restrict__ Qb, ushort* __restrict__ Kb, ushort* __restrict__ Vt,
    float* __restrict__ cacheOut)
{
    __shared__ ushort As[3][128 * 32];
    __shared__ ushort Bs[3][256 * 32];
    const int tid  = threadIdx.x;
    const int wv   = tid >> 6;
    const int lane = tid & 63;
    const int quad = lane >> 4;
    const int l16  = lane & 15;
    const int m0 = blockIdx.y * 128;
    const int n0 = blockIdx.x * 256;
    const int wm = (wv >> 1) * 32;
    const int wn = (wv & 1) * 128;

    f4v zero = {0.f, 0.f, 0.f, 0.f};
    f4v acc[2][8];                     // 32 rows (tokens) x 128 cols (d)
    #pragma unroll
    for (int i = 0; i < 2; i++)
        #pragma unroll
        for (int j = 0; j < 8; j++) acc[i][j] = zero;

    const int swz = ((lane & 3) ^ ((lane >> 3) & 3)) * 8;
    const int rS  = lane >> 2;
    const ushort* gA = A  + (size_t)(m0 + wv * 16 + rS) * Hd + swz;  // 8w x 16r = 128
    const ushort* gB = Bw + (size_t)(n0 + wv * 32 + rS) * Hd + swz;  // 8w x 32r = 256
    const int stA = (wv * 16) * 32;
    const int stB = (wv * 32) * 32;
    const int fsw = ((l16 >> 1) & 3) * 8;

    // prologue: stage tiles 0,1 (6 issues/wave), wait tile 0 (3 oldest)
    #pragma unroll
    for (int t = 0; t < 2; t++) {
        async_cp16(&As[t][stA],           gA + t * 32);
        async_cp16(&Bs[t][stB],           gB + t * 32);
        async_cp16(&Bs[t][stB + 16 * 32], gB + (size_t)16 * Hd + t * 32);
    }
    asm volatile("s_waitcnt vmcnt(3)" ::: "memory");
    __builtin_amdgcn_s_barrier();

    const int NT = Hd / 32;            // 112
    for (int t = 0; t < NT; t++) {
        const ushort* Ac = As[t % 3];
        const ushort* Bc = Bs[t % 3];
        ushort* An = (ushort*)As[(t + 2) % 3];
        ushort* Bn = (ushort*)Bs[(t + 2) % 3];
        const int kn = (t + 2) * 32;
        const bool pf = (t + 2 < NT);

        // ---- phase 0 ----
        s8v af[2], bfr[4];
        #pragma unroll
        for (int i = 0; i < 2; i++)
            af[i] = *(const s8v*)&Ac[(wm + i * 16 + l16) * 32 + ((quad * 8) ^ fsw)];
        #pragma unroll
        for (int j = 0; j < 4; j++)
            bfr[j] = *(const s8v*)&Bc[(wn + j * 16 + l16) * 32 + ((quad * 8) ^ fsw)];
        if (pf) {
            async_cp16(&An[stA], gA + kn);
            async_cp16(&Bn[stB], gB + kn);
        }
        __builtin_amdgcn_s_barrier();
        asm volatile("s_waitcnt lgkmcnt(0)" ::: "memory");
        __builtin_amdgcn_sched_barrier(0);
        __builtin_amdgcn_s_setprio(1);
        #pragma unroll
        for (int i = 0; i < 2; i++)
            #pragma unroll
            for (int j = 0; j < 4; j++)
                acc[i][j] = mfma16(af[i], bfr[j], acc[i][j]);
        __builtin_amdgcn_s_setprio(0);
        __builtin_amdgcn_s_barrier();

        // ---- phase 1 ----
        #pragma unroll
        for (int j = 0; j < 4; j++)
            bfr[j] = *(const s8v*)&Bc[(wn + (j + 4) * 16 + l16) * 32 + ((quad * 8) ^ fsw)];
        if (pf) {
            async_cp16(&Bn[stB + 16 * 32], gB + (size_t)16 * Hd + kn);
            asm volatile("s_waitcnt vmcnt(3)" ::: "memory");
        } else {
            asm volatile("s_waitcnt vmcnt(0)" ::: "memory");
        }
        __builtin_amdgcn_s_barrier();
        asm volatile("s_waitcnt lgkmcnt(0)" ::: "memory");
        __builtin_amdgcn_sched_barrier(0);
        __builtin_amdgcn_s_setprio(1);
        #pragma unroll
        for (int i = 0; i < 2; i++)
            #pragma unroll
            for (int j = 0; j < 4; j++)
                acc[i][j + 4] = mfma16(af[i], bfr[j], acc[i][j + 4]);
        __builtin_amdgcn_s_setprio(0);
        __builtin_amdgcn_s_barrier();
    }

    // ---- fused epilogue: this wave owns head slot s ----
    const int s = blockIdx.x * 2 + (wv & 1);
    float bv[8];
    #pragma unroll
    for (int j = 0; j < 8; j++) bv[j] = bias[s * 128 + j * 16 + l16];

    if (s < NHq + NKVh) {              // Q or K: RoPE
        float invf[4];
        #pragma unroll
        for (int j = 0; j < 4; j++)
            invf[j] = __expf(-0.14391156831212787f * (float)(j * 16 + l16));
        #pragma unroll
        for (int i = 0; i < 2; i++) {
            #pragma unroll
            for (int r = 0; r < 4; r++) {
                const int t = m0 + wm + i * 16 + quad * 4 + r;
                const float p = (float)pos[t];
                float od[8];
                #pragma unroll
                for (int j = 0; j < 4; j++) {
                    float sv, cv;
                    __sincosf(p * invf[j], &sv, &cv);
                    const float x1 = acc[i][j][r] + bv[j];
                    const float x2 = acc[i][j + 4][r] + bv[j + 4];
                    od[j]     = x1 * cv - x2 * sv;
                    od[j + 4] = x2 * cv + x1 * sv;
                }
                if (s < NHq) {
                    #pragma unroll
                    for (int j = 0; j < 8; j++)
                        Qb[((size_t)t * NHq + s) * Dh + j * 16 + l16] = bf16r(od[j]);
                } else {
                    const int kvh = s - NHq;
                    const int slot = slot_map[t];
                    #pragma unroll
                    for (int j = 0; j < 8; j++) {
                        const int d = j * 16 + l16;
                        Kb[((size_t)t * NKVh + kvh) * Dh + d] = bf16r(od[j]);
                        cacheOut[(size_t)slot * (NKVh * Dh) + kvh * Dh + d] = od[j];
                    }
                }
            }
        }
    } else {                           // V: no RoPE; emit V^T + cache
        const int kvh = s - NHq - NKVh;
        #pragma unroll
        for (int i = 0; i < 2; i++) {
            #pragma unroll
            for (int r = 0; r < 4; r++) {
                const int t = m0 + wm + i * 16 + quad * 4 + r;
                const int slot = slot_map[t];
                const int b = t >> 10, stok = t & 1023;
                #pragma unroll
                for (int j = 0; j < 8; j++) {
                    const float x = acc[i][j][r] + bv[j];
                    const int d = j * 16 + l16;
                    Vt[((size_t)(b * NKVh + kvh) * Dh + d) * Ss + stok] = bf16r(x);
                    cacheOut[(size_t)NBLK * BSZ * NKVh * Dh +
                             (size_t)slot * (NKVh * Dh) + kvh * Dh + d] = x;
                }
            }
        }
    }
}

// ---------------- flash attention, S^T formulation ----------------
__global__ __launch_bounds__(256, 2) void attn(
    const ushort* __restrict__ Qb, const ushort* __restrict__ Kb,
    const ushort* __restrict__ Vt, ushort* __restrict__ ctx)
{
    __shared__ ushort Ksm[128 * 128];
    __shared__ ushort Vsm[128 * 128];

    const int tid  = threadIdx.x;
    const int w    = tid >> 6;
    const int lane = tid & 63;
    const int quad = lane >> 4;
    const int l16  = lane & 15;
    const int qt = (Ss / 128 - 1) - blockIdx.x;   // heavy blocks first
    const int h  = blockIdx.y;
    const int b  = blockIdx.z;
    const int kv = h / GRP;
    const int t0 = b * Ss + qt * 128;

    s8v qf[2][4];
    #pragma unroll
    for (int nt = 0; nt < 2; nt++)
        #pragma unroll
        for (int kd = 0; kd < 4; kd++)
            qf[nt][kd] = *(const s8v*)&Qb[((size_t)(t0 + w * 32 + nt * 16 + l16) * NHq + h) * Dh
                                          + kd * 32 + quad * 8];

    f4v zero = {0.f, 0.f, 0.f, 0.f};
    f4v o[2][8];
    #pragma unroll
    for (int nt = 0; nt < 2; nt++)
        #pragma unroll
        for (int dt = 0; dt < 8; dt++) o[nt][dt] = zero;
    float mstat[2] = {-1e30f, -1e30f};
    float dstat[2] = {0.f, 0.f};

    const int srow = lane >> 4;
    const int gch  = (lane & 15) ^ (w * 4 + srow);
    const ushort* gK = Kb + (size_t)(b * Ss) * (NKVh * Dh) + kv * Dh + gch * 8;
    const ushort* gV = Vt + (size_t)(b * NKVh + kv) * Dh * Ss + gch * 8;

    const int srcq0 = ((quad & 1) << 1) | (quad >> 1);
    const int addr0 = (srcq0 * 16 + l16) * 4;
    const int addr1 = ((srcq0 ^ 1) * 16 + l16) * 4;
    const bool oddq = (quad & 1);
    const bool lowq = (quad < 2);

    for (int kt = 0; kt <= qt; kt++) {
        const bool diag = (kt == qt);

        #pragma unroll
        for (int j = 0; j < 8; j++) {
            const int row = j * 16 + w * 4 + srow;
            async_cp16(&Ksm[(j * 16 + w * 4) * 128],
                       gK + (size_t)(kt * 128 + row) * (NKVh * Dh));
            async_cp16(&Vsm[(j * 16 + w * 4) * 128],
                       gV + (size_t)row * Ss + kt * 128);
        }
        __syncthreads();

        const int smax = diag ? (2 * w + 1) : 7;
        f4v sc[8][2];
        #pragma unroll
        for (int st = 0; st < 8; st++) { sc[st][0] = zero; sc[st][1] = zero; }
        #pragma unroll
        for (int st = 0; st < 8; st++) {
            if (st > smax) continue;
            #pragma unroll
            for (int kd = 0; kd < 4; kd++) {
                s8v kf = *(const s8v*)&Ksm[((st * 16 + l16) * 16 + ((kd * 4 + quad) ^ l16)) * 8];
                sc[st][0] = mfma16(kf, qf[0][kd], sc[st][0]);
                sc[st][1] = mfma16(kf, qf[1][kd], sc[st][1]);
            }
        }

        float alpha[2];
        #pragma unroll
        for (int nt = 0; nt < 2; nt++) {
            const int qcol = w * 32 + nt * 16 + l16;
            float rowm = -1e30f;
            #pragma unroll
            for (int st = 0; st < 8; st++) {
                if (st > smax) continue;
                #pragma unroll
                for (int r = 0; r < 4; r++) {
                    float v = sc[st][nt][r] * ATTN_SCALE;
                    if (diag && (st * 16 + quad * 4 + r > qcol)) v = -1e30f;
                    sc[st][nt][r] = v;
                    rowm = fmaxf(rowm, v);
                }
            }
            rowm = fmaxf(rowm, __shfl_xor(rowm, 16, 64));
            rowm = fmaxf(rowm, __shfl_xor(rowm, 32, 64));
            const float mn = fmaxf(mstat[nt], rowm);
            const float al = __expf(mstat[nt] - mn);
            float rs = 0.f;
            #pragma unroll
            for (int st = 0; st < 8; st++) {
                if (st > smax) continue;
                #pragma unroll
                for (int r = 0; r < 4; r++) {
                    const float p = __expf(sc[st][nt][r] - mn);
                    sc[st][nt][r] = p;
                    rs += p;
                }
            }
            rs += __shfl_xor(rs, 16, 64);
            rs += __shfl_xor(rs, 32, 64);
            dstat[nt] = dstat[nt] * al + rs;
            mstat[nt] = mn;
            alpha[nt] = al;
            #pragma unroll
            for (int dt = 0; dt < 8; dt++)
                #pragma unroll
                for (int r = 0; r < 4; r++) o[nt][dt][r] *= al;
        }

        const int spmax = diag ? w : 3;
        #pragma unroll
        for (int sp = 0; sp < 4; sp++) {
            if (sp > spmax) continue;
            s8v pf[2];
            #pragma unroll
            for (int nt = 0; nt < 2; nt++) {
                const uint32_t a01 = pkbf(sc[2 * sp][nt][0],     sc[2 * sp][nt][1]);
                const uint32_t a23 = pkbf(sc[2 * sp][nt][2],     sc[2 * sp][nt][3]);
                const uint32_t b01 = pkbf(sc[2 * sp + 1][nt][0], sc[2 * sp + 1][nt][1]);
                const uint32_t b23 = pkbf(sc[2 * sp + 1][nt][2], sc[2 * sp + 1][nt][3]);
                const int r0 = __builtin_amdgcn_ds_bpermute(addr0, (int)(oddq ? b01 : a01));
                const int r1 = __builtin_amdgcn_ds_bpermute(addr1, (int)(oddq ? a01 : b01));
                const int r2 = __builtin_amdgcn_ds_bpermute(addr0, (int)(oddq ? b23 : a23));
                const int r3 = __builtin_amdgcn_ds_bpermute(addr1, (int)(oddq ? a23 : b23));
                union { int d[4]; s8v v; } u;
                u.d[0] = lowq ? r0 : r1;
                u.d[1] = lowq ? r2 : r3;
                u.d[2] = lowq ? r1 : r0;
                u.d[3] = lowq ? r3 : r2;
                pf[nt] = u.v;
            }
            #pragma unroll
            for (int dt = 0; dt < 8; dt++) {
                s8v vf = *(const s8v*)&Vsm[((dt * 16 + l16) * 16 + ((sp * 4 + quad) ^ l16)) * 8];
                o[0][dt] = mfma16(vf, pf[0], o[0][dt]);
                o[1][dt] = mfma16(vf, pf[1], o[1][dt]);
            }
        }
        __syncthreads();
    }

    #pragma unroll
    for (int nt = 0; nt < 2; nt++) {
        const float inv = 1.0f / dstat[nt];
        const int trow = t0 + w * 32 + nt * 16 + l16;
        #pragma unroll
        for (int dt = 0; dt < 8; dt++) {
            ushort4 u;
            u.x = bf16r(o[nt][dt][0] * inv);
            u.y = bf16r(o[nt][dt][1] * inv);
            u.z = bf16r(o[nt][dt][2] * inv);
            u.w = bf16r(o[nt][dt][3] * inv);
            *(ushort4*)&ctx[(size_t)trow * Hd + h * Dh + dt * 16 + quad * 4] = u;
        }
    }
}

// ---------------- launch ----------------
extern "C" void kernel_launch(void* const* d_in, const int* in_sizes, int n_in,
                              void* d_out, int out_size, void* d_ws, size_t ws_size,
                              hipStream_t stream)
{
    const int*   positions = (const int*)d_in[0];
    const float* hidden    = (const float*)d_in[1];
    const float* kvc       = (const float*)d_in[2];
    const int*   slot_map  = (const int*)d_in[4];
    const float* w_qkv     = (const float*)d_in[7];
    const float* b_qkv     = (const float*)d_in[8];
    const float* w_o       = (const float*)d_in[9];

    float* out      = (float*)d_out;                 // (T, H) fp32
    float* cacheOut = out + (size_t)Tt * Hd;         // (2,NB,BS,NKV,D) fp32

    char* ws = (char*)d_ws;
    ushort* Xb    = (ushort*)(ws);                   // T*H bf16         29360128
    ushort* Wqkvb = (ushort*)(ws + 29360128);        // 4608*3584 bf16   33030144
    ushort* Wob   = (ushort*)(ws + 62390272);        // 3584*3584 bf16   25690112
    ushort* Qb    = (ushort*)(ws + 88080384);        // T*NH*D bf16      29360128
    ushort* Kb    = (ushort*)(ws + 117440512);       // T*NKV*D bf16      4194304
    ushort* Vt    = (ushort*)(ws + 121634816);       // B*NKV*D*S bf16    4194304
    ushort* ctx   = Xb;                              // alias: Xb dead after gemm_qkv

    cvt_bf16<<<dim3(14336), 256, 0, stream>>>(hidden, Xb, 3670016);
    cvt_bf16<<<dim3(16128), 256, 0, stream>>>(w_qkv, Wqkvb, 4128768);
    cvt_bf16<<<dim3(12544), 256, 0, stream>>>(w_o, Wob, 3211264);
    copy_f4<<<dim3(8192), 256, 0, stream>>>(kvc, cacheOut, 2097152);
    gemm_qkv<<<dim3(QKVO / 256, Tt / 128), 512, 0, stream>>>(
        Xb, Wqkvb, b_qkv, positions, slot_map, Qb, Kb, Vt, cacheOut);
    attn<<<dim3(Ss / 128, NHq, Bb), 256, 0, stream>>>(Qb, Kb, Vt, ctx);
    gemm_bt<<<dim3(Hd / 256, Tt / 256), 512, 0, stream>>>(
        ctx, Wob, out, Hd, Hd);
}